// Round 17
// baseline (313.310 us; speedup 1.0000x reference)
//
#include <hip/hip_runtime.h>
#include <hip/hip_cooperative_groups.h>
#include <math.h>

namespace cg = cooperative_groups;

typedef unsigned short u16;
typedef unsigned int u32;
typedef __attribute__((ext_vector_type(8))) short short8v;    // 8 bf16 (4 VGPR)
typedef __attribute__((ext_vector_type(4))) float f32x4;

// ---------------------------------------------------------------------------
// ws layout (f32 units):
//   x1pn [b][34][34][128] bf16 @ 0          (4,734,976 f32)
//   x2b  [kb=512][b=64][k'=256] bf16 @ 7,102,464  (4,194,304 f32)
//   partial [64brow][512kb][64n] f32 @ 0 (over dead x1pn, 2,097,152)
//   w1q bf16 @ 11,300,000 (36,864 u16), w2p bf16 @ 11,330,000 (36,864 u16)
// Cooperative mega-kernel (512 blocks) with checked fallback to 5 launches.
// ---------------------------------------------------------------------------
#define X2B_OFF  7102464
#define W1Q_OFF  11300000
#define W2P_OFF  11330000
#define D1_NB 512

__device__ __forceinline__ u16 f2bf(float f) {
    union { float f; u32 i; } c; c.f = f;
    u32 r = c.i + 0x7fffu + ((c.i >> 16) & 1u);   // RNE
    return (u16)(r >> 16);
}
__device__ __forceinline__ int Sf(int i0, int m) {
    return (i0 >= 3) ? (i0 - 3 + m) : ((m <= i0) ? m : (12 + m));
}

// ---------------- P0: x1 borders + weight packs ------------------------------
__device__ void prep_work(int t, const float* __restrict__ cw1,
    const float* __restrict__ cw2, u16* __restrict__ x1pn,
    u16* __restrict__ w1q, u16* __restrict__ w2p) {
    if (t < 135168) {
        uint4 z = {0u, 0u, 0u, 0u};
        int v = t & 15, cell = t >> 4;
        int b = cell / 132, ci = cell - b * 132;
        int y, x;
        if (ci < 34)       { y = 0;       x = ci; }
        else if (ci < 68)  { y = 33;      x = ci - 34; }
        else if (ci < 100) { y = ci - 67; x = 0; }
        else               { y = ci - 99; x = 33; }
        *(uint4*)(x1pn + ((b * 34 + y) * 34 + x) * 128 + v * 8) = z;
        return;
    }
    int u0 = t - 135168;                          // 73,728 weight elements
    if (u0 < 36864) {
        int j = u0 & 7, lane = (u0 >> 3) & 63;
        int tp = u0 >> 9;
        int tap = tp % 9, pr = tp / 9;
        int n = lane & 15;
        int k = 8 * (lane >> 4) + j;
        float v = 0.f;
        if (n < 8) {
            if (k < 16) {
                int f = 4 * (k & 3) + (k >> 2);
                v = cw1[(tap * 16 + f) * 128 + 2 * pr + 16 * n];
            }
        } else {
            if (k >= 16) {
                int k2 = k - 16;
                int f = 4 * (k2 & 3) + (k2 >> 2);
                v = cw1[(tap * 16 + f) * 128 + 2 * pr + 1 + 16 * (n - 8)];
            }
        }
        w1q[u0] = f2bf(v);
    } else {
        int u = u0 - 36864;
        int j = u & 7, lane = (u >> 3) & 63;
        int nt = (u >> 9) & 1;
        int gt = u >> 10, tap = gt % 9, g = gt / 9;
        int k = 8 * (lane >> 4) + j;
        int f = 4 * (k >> 2) + (k & 3);
        int n = g + 4 * (nt * 16 + (lane & 15));
        w2p[u] = f2bf(cw2[(tap * 32 + f) * 128 + n]);
    }
}

// ---------------- P1: fused L0+L1, one (b,rq,pp) unit ------------------------
__device__ void l01_work(int bi, int t, const float* __restrict__ in,
    const float* __restrict__ cw0, const float* __restrict__ cb0,
    const u16* __restrict__ w1q, const float* __restrict__ cb1,
    u16* __restrict__ x1pn, char* x0s) {
    int xcd = bi & 7, slot = bi >> 3;    // 128 slots per xcd
    int b = xcd * 8 + (slot >> 4);
    int rem = slot & 15;
    int rq = rem >> 1, pp = rem & 1;
    int lane = t & 63, wv = t >> 6;
    int col = lane & 15, khi = lane >> 4;

    // ---- phase A: compute x0 slab (6 rows, padded cols, swizzled) ----
    {
        if (t < 96) {
            int row_s = t >> 4, side = (t >> 3) & 1, ch16 = t & 7;
            int p = row_s * 34 + side * 33;
            uint4 z = {0u, 0u, 0u, 0u};
            *(uint4*)(x0s + p * 128 + ((ch16 ^ (p & 7)) << 4)) = z;
        }
        short8v Bf[4];
#pragma unroll
        for (int nb = 0; nb < 4; ++nb) {
            union { short8v v; u16 e[8]; } B;
#pragma unroll
            for (int j = 0; j < 8; ++j) {
                int k = 8 * khi + j;
                B.e[j] = (k < 27) ? f2bf(cw0[k * 64 + nb * 16 + col]) : (u16)0;
            }
            Bf[nb] = B.v;
        }
        float bias[4];
#pragma unroll
        for (int nb = 0; nb < 4; ++nb) bias[nb] = cb0[nb * 16 + col];

        for (int i = 0; i < 3; ++i) {
            int tt = wv * 3 + i;             // 0..11: 6 rows x 2 halves
            int row_s = tt >> 1, xhalf = tt & 1;
            int y_img = rq * 4 - 1 + row_s;
            bool yv = (unsigned)y_img < 32u;
            int x_pix = xhalf * 16 + col;
            union { short8v v; u16 e[8]; } A;
#pragma unroll
            for (int j = 0; j < 8; ++j) {
                int k = 8 * khi + j;
                float v = 0.f;
                if (k < 27) {
                    int tap = k / 3, c = k - 3 * tap;
                    int dy = tap / 3, dx = tap - 3 * dy;
                    int y = y_img + dy - 1, x = x_pix + dx - 1;
                    if ((unsigned)y < 32u && (unsigned)x < 32u)
                        v = in[((b * 32 + y) * 32 + x) * 3 + c];
                }
                A.e[j] = f2bf(v);
            }
            f32x4 acc[4];
#pragma unroll
            for (int nb = 0; nb < 4; ++nb) {
                f32x4 ci = {bias[nb], bias[nb], bias[nb], bias[nb]};
                acc[nb] = __builtin_amdgcn_mfma_f32_16x16x32_bf16(A.v, Bf[nb], ci, 0, 0, 0);
            }
#pragma unroll
            for (int r = 0; r < 4; ++r) {
                int px_l = 4 * khi + r;
                float v0 = yv ? fmaxf(acc[0][r], 0.f) : 0.f;
                float v1 = yv ? fmaxf(acc[1][r], 0.f) : 0.f;
                float v2 = yv ? fmaxf(acc[2][r], 0.f) : 0.f;
                float v3 = yv ? fmaxf(acc[3][r], 0.f) : 0.f;
                u32 lo = (u32)f2bf(v0) | ((u32)f2bf(v1) << 16);
                u32 hi = (u32)f2bf(v2) | ((u32)f2bf(v3) << 16);
                uint2 pk = {lo, hi};
                int p = row_s * 34 + xhalf * 16 + px_l + 1;
                int dst = p * 128 + (((col >> 1) ^ (p & 7)) << 4) + (col & 1) * 8;
                *(uint2*)(x0s + dst) = pk;
            }
        }
    }
    __syncthreads();

    // ---- phase B: l1 MFMA for this unit's pp ----
    {
        int pr = wv * 2 + pp;            // i0-pair
        int i0a = 2 * pr, i0b = 2 * pr + 1;
        int i0g = (khi >= 2) ? i0b : i0a;
        int mb = 2 * (khi & 1);
        int o0 = 8 * Sf(i0g, mb), o1 = 8 * Sf(i0g, mb + 1);

        short8v wf[9];
#pragma unroll
        for (int tap = 0; tap < 9; ++tap)
            wf[tap] = *(const short8v*)(w1q + ((pr * 9 + tap) * 64 + lane) * 8);

        int node = (col < 8) ? (i0a + 16 * col) : (i0b + 16 * (col - 8));
        float bv = cb1[node];
        int cperm = 32 * (node & 3) + (node >> 2);

        for (int mt = 0; mt < 8; ++mt) {
            int row_l = mt >> 1, cbase = (mt & 1) * 16;
            f32x4 acc = {bv, bv, bv, bv};
            int pbase = row_l * 34 + cbase + col;
#pragma unroll
            for (int tap = 0; tap < 9; ++tap) {
                const int dy = tap / 3, dx = tap % 3;
                int p = pbase + dy * 34 + dx;
                int sw = (p & 7) << 4;
                int base = p * 128;
                union { short8v v; uint2 h[2]; } A;
                A.h[0] = *(const uint2*)(x0s + base + (o0 ^ sw));
                A.h[1] = *(const uint2*)(x0s + base + (o1 ^ sw));
                acc = __builtin_amdgcn_mfma_f32_16x16x32_bf16(A.v, wf[tap], acc, 0, 0, 0);
            }
            int prow = rq * 4 + row_l + 1;
            u16* ob = x1pn + ((size_t)(b * 34 + prow) * 34) * 128 + cperm;
#pragma unroll
            for (int r = 0; r < 4; ++r) {
                int pcol = cbase + khi * 4 + r + 1;
                ob[pcol * 128] = f2bf(fmaxf(acc[r], 0.f));
            }
        }
    }
}

// ---------------- P2: l2 MFMA, one slab-unit ---------------------------------
__device__ void l2_work(int bi, int t, const u16* __restrict__ x1pn,
    const u16* __restrict__ w2p, const float* __restrict__ cb2,
    u16* __restrict__ x2b, char* lds) {
    u16* x1s = (u16*)lds;                // 13,056 B
    int xcd = bi & 7, slot = bi >> 3;
    int b = xcd * 8 + (slot >> 5);
    int rem = slot & 31;
    int rq = rem >> 2, g = rem & 3;
    int lane = t & 63, wvi = t >> 6;
    int col = lane & 15, khi = lane >> 4;

    {
        const u16* src = x1pn + (size_t)(b * 34 + rq * 4) * (34 * 128) + g * 32;
        for (int c = t; c < 816; c += 256) {
            int row = c / 136, e = c - row * 136;
            int px = e >> 2, part = e & 3;
            uint4 v = *(const uint4*)(src + (size_t)row * (34 * 128) + px * 128 + part * 8);
            *(uint4*)(x1s + (row * 34 + px) * 32 + part * 8) = v;
        }
    }
    __syncthreads();

    short8v wf[9][2];
#pragma unroll
    for (int tap = 0; tap < 9; ++tap)
#pragma unroll
        for (int nt = 0; nt < 2; ++nt)
            wf[tap][nt] = *(const short8v*)(w2p + (((g * 9 + tap) * 2 + nt) * 64 + lane) * 8);

    float bv0 = cb2[g + 4 * col];
    float bv1 = cb2[g + 4 * (16 + col)];

    int y = rq * 4 + wvi;
    f32x4 acc[2][2];
    acc[0][0] = (f32x4){bv0, bv0, bv0, bv0}; acc[0][1] = (f32x4){bv1, bv1, bv1, bv1};
    acc[1][0] = acc[0][0];                   acc[1][1] = acc[0][1];
#pragma unroll
    for (int tap = 0; tap < 9; ++tap) {
        const int dy = tap / 3, dx = tap % 3;
#pragma unroll
        for (int ms = 0; ms < 2; ++ms) {
            int px = (wvi + dy) * 34 + ms * 16 + col + dx;
            short8v a = *(const short8v*)(x1s + px * 32 + khi * 8);
            acc[ms][0] = __builtin_amdgcn_mfma_f32_16x16x32_bf16(a, wf[tap][0], acc[ms][0], 0, 0, 0);
            acc[ms][1] = __builtin_amdgcn_mfma_f32_16x16x32_bf16(a, wf[tap][1], acc[ms][1], 0, 0, 0);
        }
    }
#pragma unroll
    for (int ms = 0; ms < 2; ++ms)
#pragma unroll
        for (int nt = 0; nt < 2; ++nt) {
            size_t kbase = ((size_t)((g * 2 + nt) * 64 + y * 2 + ms) * 64 + b) * 256;
#pragma unroll
            for (int r = 0; r < 4; ++r) {
                x2b[kbase + (4 * khi + r) * 16 + col] = f2bf(fmaxf(acc[ms][nt][r], 0.f));
            }
        }
}

// ---------------- P3: d1 MFMA -------------------------------------------------
__device__ void d1_work(int kb, int t, const u16* __restrict__ x2b,
    const float* __restrict__ dw1, float* __restrict__ partial) {
    int lane = t & 63, w = t >> 6;
    int col = lane & 15, khi = lane >> 4;
    int n = 16 * w + col;
    f32x4 acc[4];
#pragma unroll
    for (int m = 0; m < 4; ++m) acc[m] = (f32x4){0.f, 0.f, 0.f, 0.f};

#pragma unroll 2
    for (int ks = 0; ks < 8; ++ks) {
        int kbase = kb * 256 + ks * 32 + 8 * khi;
        int c0 = kbase & 15;
        int q = kbase >> 4;
        int g = q >> 11, nt = (q >> 10) & 1, pix = q & 1023;
        union { short8v v; u16 e[8]; } Bf;
        if (n < 50) {
            const float* wp = dw1 + (size_t)(pix * 128 + g + 64 * nt + 4 * c0) * 50 + n;
#pragma unroll
            for (int j = 0; j < 8; ++j) Bf.e[j] = f2bf(wp[j * 200]);
        } else {
            Bf.v = (short8v)0;
        }
#pragma unroll
        for (int m = 0; m < 4; ++m) {
            short8v A = *(const short8v*)(x2b + ((size_t)kb * 64 + m * 16 + col) * 256
                                          + ks * 32 + 8 * khi);
            acc[m] = __builtin_amdgcn_mfma_f32_16x16x32_bf16(A, Bf.v, acc[m], 0, 0, 0);
        }
    }
#pragma unroll
    for (int m = 0; m < 4; ++m)
#pragma unroll
        for (int r = 0; r < 4; ++r) {
            int brow = m * 16 + khi * 4 + r;
            partial[((size_t)brow * D1_NB + kb) * 64 + n] = acc[m][r];
        }
}

// ---------------- P4: reduce + dense2 + softmax ------------------------------
__device__ void rd2_work(int b, int t, const float* __restrict__ partial,
    const float* __restrict__ db1, const float* __restrict__ dw2,
    const float* __restrict__ db2, float* __restrict__ out, char* lds) {
    float* sm = (float*)lds;             // [4][64]
    float* hs = sm + 256;                // [64]
    float* as = hs + 64;                 // [10]
    int j = t & 63, pp = t >> 6;         // pp 0..3
    const float* pb = partial + ((size_t)b * D1_NB + pp * 128) * 64 + j;
    float s0 = 0.f, s1 = 0.f, s2 = 0.f, s3 = 0.f;
    for (int cb = 0; cb < 128; cb += 4) {
        s0 += pb[(cb + 0) * 64];
        s1 += pb[(cb + 1) * 64];
        s2 += pb[(cb + 2) * 64];
        s3 += pb[(cb + 3) * 64];
    }
    sm[pp * 64 + j] = (s0 + s1) + (s2 + s3);
    __syncthreads();
    if (pp == 0) {
        float h = (sm[j] + sm[64 + j]) + (sm[128 + j] + sm[192 + j]);
        hs[j] = (j < 50) ? fmaxf(h + db1[j], 0.f) : 0.f;
    }
    __syncthreads();
    if (t < 10) {
        float a = db2[t];
        for (int i = 0; i < 50; ++i) a += hs[i] * dw2[i * 10 + t];
        as[t] = a;
    }
    __syncthreads();
    if (t == 0) {
        float mx = as[0];
#pragma unroll
        for (int q = 1; q < 10; ++q) mx = fmaxf(mx, as[q]);
        float e[10], s = 0.f;
#pragma unroll
        for (int q = 0; q < 10; ++q) { e[q] = expf(as[q] - mx); s += e[q]; }
        float inv = 1.f / s;
#pragma unroll
        for (int q = 0; q < 10; ++q) out[b * 10 + q] = e[q] * inv;
    }
}

// ---------------- cooperative mega-kernel: 512 blocks ------------------------
__global__ __launch_bounds__(256, 2) void meganet(
    const float* __restrict__ in, const float* __restrict__ cw0,
    const float* __restrict__ cb0, const float* __restrict__ cw1,
    const float* __restrict__ cb1, const float* __restrict__ cw2,
    const float* __restrict__ cb2, const float* __restrict__ dw1,
    const float* __restrict__ db1, const float* __restrict__ dw2,
    const float* __restrict__ db2,
    u16* x1pn, u16* x2b, float* partial, u16* w1q, u16* w2p, float* out) {
    __shared__ __align__(16) char smem[26112];
    cg::grid_group grid = cg::this_grid();
    int bid = blockIdx.x, t = threadIdx.x;

    // P0: 208,896 items over 512 blocks x 2 rounds
#pragma unroll
    for (int u = 0; u < 2; ++u) {
        int idx = (bid + u * 512) * 256 + t;
        if (idx < 208896) prep_work(idx, cw1, cw2, x1pn, w1q, w2p);
    }
    grid.sync();

    // P1: 1024 l01 units, 2 per block
    for (int u = 0; u < 2; ++u) {
        l01_work(bid + u * 512, t, in, cw0, cb0, w1q, cb1, x1pn, smem);
        __syncthreads();
    }
    grid.sync();

    // P2: 2048 l2 units, 4 per block
    for (int u = 0; u < 4; ++u) {
        l2_work(bid + u * 512, t, x1pn, w2p, cb2, x2b, smem);
        __syncthreads();
    }
    grid.sync();

    // P3: 512 d1 units
    d1_work(bid, t, x2b, dw1, partial);
    grid.sync();

    // P4: 64 rd2 units
    if (bid < 64) rd2_work(bid, t, partial, db1, dw2, db2, out, smem);
}

// ---------------- standalone fallback wrappers (R13/R15 proven path) ---------
__global__ __launch_bounds__(256) void prep_g(const float* __restrict__ cw1,
    const float* __restrict__ cw2, u16* x1pn, u16* w1q, u16* w2p) {
    prep_work(blockIdx.x * 256 + threadIdx.x, cw1, cw2, x1pn, w1q, w2p);
}
__global__ __launch_bounds__(256) void l01_g(const float* __restrict__ in,
    const float* __restrict__ cw0, const float* __restrict__ cb0,
    const u16* __restrict__ w1q, const float* __restrict__ cb1, u16* x1pn) {
    __shared__ __align__(16) char smem[26112];
    l01_work(blockIdx.x, threadIdx.x, in, cw0, cb0, w1q, cb1, x1pn, smem);
}
__global__ __launch_bounds__(256) void l2_g(const u16* __restrict__ x1pn,
    const u16* __restrict__ w2p, const float* __restrict__ cb2, u16* x2b) {
    __shared__ __align__(16) char smem[13056];
    l2_work(blockIdx.x, threadIdx.x, x1pn, w2p, cb2, x2b, smem);
}
__global__ __launch_bounds__(256) void d1_g(const u16* __restrict__ x2b,
    const float* __restrict__ dw1, float* partial) {
    d1_work(blockIdx.x, threadIdx.x, x2b, dw1, partial);
}
__global__ __launch_bounds__(256) void rd2_g(const float* __restrict__ partial,
    const float* __restrict__ db1, const float* __restrict__ dw2,
    const float* __restrict__ db2, float* out) {
    __shared__ __align__(16) char smem[1536];
    rd2_work(blockIdx.x, threadIdx.x, partial, db1, dw2, db2, out, smem);
}

// -----------------------------------------------------------------------------
extern "C" void kernel_launch(void* const* d_in, const int* in_sizes, int n_in,
                              void* d_out, int out_size, void* d_ws, size_t ws_size,
                              hipStream_t stream) {
    const float* in_  = (const float*)d_in[0];
    const float* cw0 = (const float*)d_in[1];
    const float* cb0 = (const float*)d_in[2];
    const float* cw1 = (const float*)d_in[3];
    const float* cb1 = (const float*)d_in[4];
    const float* cw2 = (const float*)d_in[5];
    const float* cb2 = (const float*)d_in[6];
    const float* dw1 = (const float*)d_in[7];
    const float* db1 = (const float*)d_in[8];
    const float* dw2 = (const float*)d_in[9];
    const float* db2 = (const float*)d_in[10];
    float* outp = (float*)d_out;

    float* ws = (float*)d_ws;
    u16* x1pn = (u16*)ws;
    u16* x2b  = (u16*)(ws + X2B_OFF);
    float* partial = ws;                  // over dead x1pn
    u16* w1q  = (u16*)(ws + W1Q_OFF);
    u16* w2p  = (u16*)(ws + W2P_OFF);

    void* args[] = {
        (void*)&in_, (void*)&cw0, (void*)&cb0, (void*)&cw1, (void*)&cb1,
        (void*)&cw2, (void*)&cb2, (void*)&dw1, (void*)&db1, (void*)&dw2,
        (void*)&db2, (void*)&x1pn, (void*)&x2b, (void*)&partial,
        (void*)&w1q, (void*)&w2p, (void*)&outp
    };
    hipError_t e = hipLaunchCooperativeKernel((void*)meganet, dim3(512),
                                              dim3(256), args, 0, stream);
    if (e != hipSuccess) {
        // proven 5-kernel path (R13/R15 behavior)
        prep_g<<<816, 256, 0, stream>>>(cw1, cw2, x1pn, w1q, w2p);
        l01_g<<<1024, 256, 0, stream>>>(in_, cw0, cb0, w1q, cb1, x1pn);
        l2_g<<<2048, 256, 0, stream>>>(x1pn, w2p, cb2, x2b);
        d1_g<<<512, 256, 0, stream>>>(x2b, dw1, partial);
        rd2_g<<<64, 256, 0, stream>>>(partial, db1, dw2, db2, outp);
    }
}

// Round 18
// 62.844 us; speedup vs baseline: 4.9855x; 4.9855x over previous
//
#include <hip/hip_runtime.h>
#include <math.h>

typedef unsigned short u16;
typedef unsigned int u32;
typedef __attribute__((ext_vector_type(8))) short short8v;    // 8 bf16 (4 VGPR)
typedef __attribute__((ext_vector_type(4))) float f32x4;

// ---------------------------------------------------------------------------
// ws layout (f32 units):
//   x1pn [b][34][34][128] bf16 @ 0          (4,734,976 f32)
//   x0pn [b][34][34][64]  bf16 @ 4,734,976  (2,367,488 f32)
//   x2b  [kb=512][b=64][k'=256] bf16 @ 7,102,464  (4,194,304 f32)
//   partial [64brow][512kb][64n] f32 @ 0 (over dead x1pn, 2,097,152)
//   w1q bf16 @ 11,300,000 (36,864 u16), w2p bf16 @ 11,330,000 (36,864 u16)
// Proven-best configuration (R13, 62.5 us).
// ---------------------------------------------------------------------------
#define X0PN_OFF 4734976
#define X2B_OFF  7102464
#define W1Q_OFF  11300000
#define W2P_OFF  11330000

__device__ __forceinline__ u16 f2bf(float f) {
    union { float f; u32 i; } c; c.f = f;
    u32 r = c.i + 0x7fffu + ((c.i >> 16) & 1u);   // RNE
    return (u16)(r >> 16);
}
__device__ __forceinline__ int Sf(int i0, int m) {
    return (i0 >= 3) ? (i0 - 3 + m) : ((m <= i0) ? m : (12 + m));
}

// ---------------- prep (borders + weight packs) fused with l0 MFMA -----------
__global__ __launch_bounds__(256) void prep_l0(const float* __restrict__ cw1,
    const float* __restrict__ cw2, const float* __restrict__ in,
    const float* __restrict__ cw0, const float* __restrict__ cb0,
    u16* __restrict__ x0pn, u16* __restrict__ x1pn,
    u16* __restrict__ w1q, u16* __restrict__ w2p) {
    int bi = blockIdx.x;
    if (bi < 1080) {
        int t = bi * 256 + threadIdx.x;           // 276,480 total
        if (t < 202752) {
            uint4 z = {0u, 0u, 0u, 0u};
            int cell, v; u16* base; int nch;
            if (t < 67584) { v = t & 7; cell = t >> 3; base = x0pn; nch = 64; }
            else { int u = t - 67584; v = u & 15; cell = u >> 4; base = x1pn; nch = 128; }
            int b = cell / 132, ci = cell - b * 132;
            int y, x;
            if (ci < 34)       { y = 0;       x = ci; }
            else if (ci < 68)  { y = 33;      x = ci - 34; }
            else if (ci < 100) { y = ci - 67; x = 0; }
            else               { y = ci - 99; x = 33; }
            *(uint4*)(base + ((b * 34 + y) * 34 + x) * nch + v * 8) = z;
            return;
        }
        int u0 = t - 202752;                      // 73,728 weight elements
        if (u0 < 36864) {
            int j = u0 & 7, lane = (u0 >> 3) & 63;
            int tp = u0 >> 9;
            int tap = tp % 9, pr = tp / 9;
            int n = lane & 15;
            int k = 8 * (lane >> 4) + j;
            float v = 0.f;
            if (n < 8) {
                if (k < 16) {
                    int f = 4 * (k & 3) + (k >> 2);
                    v = cw1[(tap * 16 + f) * 128 + 2 * pr + 16 * n];
                }
            } else {
                if (k >= 16) {
                    int k2 = k - 16;
                    int f = 4 * (k2 & 3) + (k2 >> 2);
                    v = cw1[(tap * 16 + f) * 128 + 2 * pr + 1 + 16 * (n - 8)];
                }
            }
            w1q[u0] = f2bf(v);
        } else {
            int u = u0 - 36864;
            int j = u & 7, lane = (u >> 3) & 63;
            int nt = (u >> 9) & 1;
            int gt = u >> 10, tap = gt % 9, g = gt / 9;
            int k = 8 * (lane >> 4) + j;
            int f = 4 * (k >> 2) + (k & 3);
            int n = g + 4 * (nt * 16 + (lane & 15));
            w2p[u] = f2bf(cw2[(tap * 32 + f) * 128 + n]);
        }
        return;
    }
    // ---- l0 path: MFMA im2col, K=27 pad 32; k = 3*tap + c; 512 blocks ----
    int lb = bi - 1080;                  // 512 = 64 img x 8
    int b = lb >> 3, sub = lb & 7;
    int t = threadIdx.x, lane = t & 63, wv = t >> 6;
    int col = lane & 15, khi = lane >> 4;

    short8v Bf[4];
#pragma unroll
    for (int nb = 0; nb < 4; ++nb) {
        union { short8v v; u16 e[8]; } B;
#pragma unroll
        for (int j = 0; j < 8; ++j) {
            int k = 8 * khi + j;
            B.e[j] = (k < 27) ? f2bf(cw0[k * 64 + nb * 16 + col]) : (u16)0;
        }
        Bf[nb] = B.v;
    }
    float bias[4];
#pragma unroll
    for (int nb = 0; nb < 4; ++nb) bias[nb] = cb0[nb * 16 + col];

    for (int it = 0; it < 2; ++it) {
        int tile = sub * 8 + wv * 2 + it;      // 0..63
        int py = tile >> 1, px0 = (tile & 1) * 16;
        union { short8v v; u16 e[8]; } A;
#pragma unroll
        for (int j = 0; j < 8; ++j) {
            int k = 8 * khi + j;
            float v = 0.f;
            if (k < 27) {
                int tap = k / 3, c = k - 3 * tap;
                int dy = tap / 3, dx = tap - 3 * dy;
                int y = py + dy - 1, x = px0 + col + dx - 1;
                if ((unsigned)y < 32u && (unsigned)x < 32u)
                    v = in[((b * 32 + y) * 32 + x) * 3 + c];
            }
            A.e[j] = f2bf(v);
        }
        f32x4 acc[4];
#pragma unroll
        for (int nb = 0; nb < 4; ++nb) {
            f32x4 ci = {bias[nb], bias[nb], bias[nb], bias[nb]};
            acc[nb] = __builtin_amdgcn_mfma_f32_16x16x32_bf16(A.v, Bf[nb], ci, 0, 0, 0);
        }
#pragma unroll
        for (int r = 0; r < 4; ++r) {
            int px_l = 4 * khi + r;
            u32 lo = (u32)f2bf(fmaxf(acc[0][r], 0.f)) | ((u32)f2bf(fmaxf(acc[1][r], 0.f)) << 16);
            u32 hi = (u32)f2bf(fmaxf(acc[2][r], 0.f)) | ((u32)f2bf(fmaxf(acc[3][r], 0.f)) << 16);
            uint2 pk = {lo, hi};
            *(uint2*)(x0pn + ((size_t)(b * 34 + py + 1) * 34 + px0 + px_l + 1) * 64 + 4 * col) = pk;
        }
    }
}

// ---------------- Layer 1: MFMA, i0-paired, 1024 blocks ----------------------
__global__ __launch_bounds__(256) void l1_mfma(const u16* __restrict__ x0pn,
    const u16* __restrict__ w1q, const float* __restrict__ cb1, u16* __restrict__ x1pn) {
    __shared__ __align__(16) unsigned char x0s[26112];   // 6 rows x 34 x 64ch bf16
    int bi = blockIdx.x;                 // 1024; XCD-swizzled
    int xcd = bi & 7, slot = bi >> 3;    // 128 slots per xcd
    int b = xcd * 8 + (slot >> 4);
    int rem = slot & 15;
    int rq = rem >> 1, pp = rem & 1;
    int t = threadIdx.x, lane = t & 63, wv = t >> 6;

    {
        const u16* src = x0pn + (size_t)(b * 1156 + rq * 136) * 64;
        for (int c = t; c < 1632; c += 256) {
            uint4 v = *(const uint4*)(src + c * 8);
            int p = c >> 3;
            int dst = (c * 16) ^ ((p & 7) << 4);
            *(uint4*)(x0s + dst) = v;
        }
    }
    __syncthreads();

    int col = lane & 15, khi = lane >> 4;

    int pr = pp * 4 + wv;                // i0-pair 0..7
    int i0a = 2 * pr, i0b = 2 * pr + 1;
    int i0g = (khi >= 2) ? i0b : i0a;
    int mb = 2 * (khi & 1);
    int o0 = 8 * Sf(i0g, mb), o1 = 8 * Sf(i0g, mb + 1);

    short8v wf[9];
#pragma unroll
    for (int tap = 0; tap < 9; ++tap)
        wf[tap] = *(const short8v*)(w1q + ((pr * 9 + tap) * 64 + lane) * 8);

    int node = (col < 8) ? (i0a + 16 * col) : (i0b + 16 * (col - 8));
    float bv = cb1[node];
    int cperm = 32 * (node & 3) + (node >> 2);

    for (int mt = 0; mt < 8; ++mt) {
        int row_l = mt >> 1, cbase = (mt & 1) * 16;
        f32x4 acc = {bv, bv, bv, bv};
        int pbase = row_l * 34 + cbase + col;
#pragma unroll
        for (int tap = 0; tap < 9; ++tap) {
            const int dy = tap / 3, dx = tap % 3;
            int p = pbase + dy * 34 + dx;
            int sw = (p & 7) << 4;
            int base = p * 128;
            union { short8v v; uint2 h[2]; } A;
            A.h[0] = *(const uint2*)(x0s + base + (o0 ^ sw));
            A.h[1] = *(const uint2*)(x0s + base + (o1 ^ sw));
            acc = __builtin_amdgcn_mfma_f32_16x16x32_bf16(A.v, wf[tap], acc, 0, 0, 0);
        }
        int prow = rq * 4 + row_l + 1;
        u16* ob = x1pn + ((size_t)(b * 34 + prow) * 34) * 128 + cperm;
#pragma unroll
        for (int r = 0; r < 4; ++r) {
            int pcol = cbase + khi * 4 + r + 1;
            ob[pcol * 128] = f2bf(fmaxf(acc[r], 0.f));
        }
    }
}

// ---------------- Layer 2: MFMA, LDS strips; x2b [kb][b][k'] -----------------
__global__ __launch_bounds__(256) void l2_mfma(const u16* __restrict__ x1pn,
    const u16* __restrict__ w2p, const float* __restrict__ cb2, u16* __restrict__ x2b) {
    __shared__ __align__(16) u16 x1s[6 * 34 * 32];   // 13,056 B
    int bi = blockIdx.x;                 // 2048; XCD-swizzled
    int xcd = bi & 7, slot = bi >> 3;
    int b = xcd * 8 + (slot >> 5);
    int rem = slot & 31;
    int rq = rem >> 2, g = rem & 3;
    int t = threadIdx.x, lane = t & 63, wvi = t >> 6;
    int col = lane & 15, khi = lane >> 4;

    {
        const u16* src = x1pn + (size_t)(b * 34 + rq * 4) * (34 * 128) + g * 32;
        for (int c = t; c < 816; c += 256) {
            int row = c / 136, e = c - row * 136;
            int px = e >> 2, part = e & 3;
            uint4 v = *(const uint4*)(src + (size_t)row * (34 * 128) + px * 128 + part * 8);
            *(uint4*)(x1s + (row * 34 + px) * 32 + part * 8) = v;
        }
    }
    __syncthreads();

    short8v wf[9][2];
#pragma unroll
    for (int tap = 0; tap < 9; ++tap)
#pragma unroll
        for (int nt = 0; nt < 2; ++nt)
            wf[tap][nt] = *(const short8v*)(w2p + (((g * 9 + tap) * 2 + nt) * 64 + lane) * 8);

    float bv0 = cb2[g + 4 * col];
    float bv1 = cb2[g + 4 * (16 + col)];

    int y = rq * 4 + wvi;
    f32x4 acc[2][2];
    acc[0][0] = (f32x4){bv0, bv0, bv0, bv0}; acc[0][1] = (f32x4){bv1, bv1, bv1, bv1};
    acc[1][0] = acc[0][0];                   acc[1][1] = acc[0][1];
#pragma unroll
    for (int tap = 0; tap < 9; ++tap) {
        const int dy = tap / 3, dx = tap % 3;
#pragma unroll
        for (int ms = 0; ms < 2; ++ms) {
            int px = (wvi + dy) * 34 + ms * 16 + col + dx;
            short8v a = *(const short8v*)(x1s + px * 32 + khi * 8);
            acc[ms][0] = __builtin_amdgcn_mfma_f32_16x16x32_bf16(a, wf[tap][0], acc[ms][0], 0, 0, 0);
            acc[ms][1] = __builtin_amdgcn_mfma_f32_16x16x32_bf16(a, wf[tap][1], acc[ms][1], 0, 0, 0);
        }
    }
    // store: x2b[kb][b][k'], kb = (g*2+nt)*64 + y*2+ms, k' = (4khi+r)*16 + col
#pragma unroll
    for (int ms = 0; ms < 2; ++ms)
#pragma unroll
        for (int nt = 0; nt < 2; ++nt) {
            size_t kbase = ((size_t)((g * 2 + nt) * 64 + y * 2 + ms) * 64 + b) * 256;
#pragma unroll
            for (int r = 0; r < 4; ++r) {
                x2b[kbase + (4 * khi + r) * 16 + col] = f2bf(fmaxf(acc[ms][nt][r], 0.f));
            }
        }
}

// ---------------- Dense 1 MFMA: contiguous A-panel per block -----------------
#define D1_NB 512
__global__ __launch_bounds__(256) void d1_mfma(const u16* __restrict__ x2b,
                                               const float* __restrict__ dw1,
                                               float* __restrict__ partial) {
    int kb = blockIdx.x;                 // K-chunk of 256
    int t = threadIdx.x, lane = t & 63, w = t >> 6;
    int col = lane & 15, khi = lane >> 4;
    int n = 16 * w + col;                // output column (50 valid of 64)
    f32x4 acc[4];
#pragma unroll
    for (int m = 0; m < 4; ++m) acc[m] = (f32x4){0.f, 0.f, 0.f, 0.f};

#pragma unroll 2
    for (int ks = 0; ks < 8; ++ks) {
        int kbase = kb * 256 + ks * 32 + 8 * khi;
        int c0 = kbase & 15;
        int q = kbase >> 4;
        int g = q >> 11, nt = (q >> 10) & 1, pix = q & 1023;
        union { short8v v; u16 e[8]; } Bf;
        if (n < 50) {
            const float* wp = dw1 + (size_t)(pix * 128 + g + 64 * nt + 4 * c0) * 50 + n;
#pragma unroll
            for (int j = 0; j < 8; ++j) Bf.e[j] = f2bf(wp[j * 200]);
        } else {
            Bf.v = (short8v)0;
        }
#pragma unroll
        for (int m = 0; m < 4; ++m) {
            short8v A = *(const short8v*)(x2b + ((size_t)kb * 64 + m * 16 + col) * 256
                                          + ks * 32 + 8 * khi);
            acc[m] = __builtin_amdgcn_mfma_f32_16x16x32_bf16(A, Bf.v, acc[m], 0, 0, 0);
        }
    }
#pragma unroll
    for (int m = 0; m < 4; ++m)
#pragma unroll
        for (int r = 0; r < 4; ++r) {
            int brow = m * 16 + khi * 4 + r;
            partial[((size_t)brow * D1_NB + kb) * 64 + n] = acc[m][r];
        }
}

// ---------------- Fused reduce + dense2 + softmax: 64 blocks x 1024 ----------
__global__ __launch_bounds__(1024) void rd2_kernel(const float* __restrict__ partial,
    const float* __restrict__ db1, const float* __restrict__ dw2,
    const float* __restrict__ db2, float* __restrict__ out) {
    __shared__ float sm[16][64];
    __shared__ float hs[64];
    __shared__ float as[10];
    int b = blockIdx.x;                  // batch row
    int t = threadIdx.x;
    int j = t & 63, pp = t >> 6;         // pp 0..15
    const float* pb = partial + ((size_t)b * D1_NB + pp * 32) * 64 + j;
    float s0 = 0.f, s1 = 0.f, s2 = 0.f, s3 = 0.f;
    for (int cb = 0; cb < 32; cb += 4) {
        s0 += pb[(cb + 0) * 64];
        s1 += pb[(cb + 1) * 64];
        s2 += pb[(cb + 2) * 64];
        s3 += pb[(cb + 3) * 64];
    }
    sm[pp][j] = (s0 + s1) + (s2 + s3);
    __syncthreads();
    if (pp == 0) {
        float h = 0.f;
#pragma unroll
        for (int q = 0; q < 16; ++q) h += sm[q][j];
        hs[j] = (j < 50) ? fmaxf(h + db1[j], 0.f) : 0.f;
    }
    __syncthreads();
    if (t < 10) {
        float a = db2[t];
        for (int i = 0; i < 50; ++i) a += hs[i] * dw2[i * 10 + t];
        as[t] = a;
    }
    __syncthreads();
    if (t == 0) {
        float mx = as[0];
#pragma unroll
        for (int q = 1; q < 10; ++q) mx = fmaxf(mx, as[q]);
        float e[10], s = 0.f;
#pragma unroll
        for (int q = 0; q < 10; ++q) { e[q] = expf(as[q] - mx); s += e[q]; }
        float inv = 1.f / s;
#pragma unroll
        for (int q = 0; q < 10; ++q) out[b * 10 + q] = e[q] * inv;
    }
}

// -----------------------------------------------------------------------------
extern "C" void kernel_launch(void* const* d_in, const int* in_sizes, int n_in,
                              void* d_out, int out_size, void* d_ws, size_t ws_size,
                              hipStream_t stream) {
    const float* inputs = (const float*)d_in[0];
    const float* cw0 = (const float*)d_in[1];
    const float* cb0 = (const float*)d_in[2];
    const float* cw1 = (const float*)d_in[3];
    const float* cb1 = (const float*)d_in[4];
    const float* cw2 = (const float*)d_in[5];
    const float* cb2 = (const float*)d_in[6];
    const float* dw1 = (const float*)d_in[7];
    const float* db1 = (const float*)d_in[8];
    const float* dw2 = (const float*)d_in[9];
    const float* db2 = (const float*)d_in[10];
    float* out = (float*)d_out;

    float* ws = (float*)d_ws;
    u16* x1pn = (u16*)ws;
    u16* x0pn = (u16*)(ws + X0PN_OFF);
    u16* x2b  = (u16*)(ws + X2B_OFF);
    float* partial = ws;                  // over dead x1pn (8.4 MB < 18.9 MB)
    u16* w1q  = (u16*)(ws + W1Q_OFF);
    u16* w2p  = (u16*)(ws + W2P_OFF);

    prep_l0<<<1592, 256, 0, stream>>>(cw1, cw2, inputs, cw0, cb0, x0pn, x1pn, w1q, w2p);
    l1_mfma<<<1024, 256, 0, stream>>>(x0pn, w1q, cb1, x1pn);
    l2_mfma<<<2048, 256, 0, stream>>>(x1pn, w2p, cb2, x2b);
    d1_mfma<<<D1_NB, 256, 0, stream>>>(x2b, dw1, partial);
    rd2_kernel<<<64, 1024, 0, stream>>>(partial, db1, dw2, db2, out);
}